// Round 1
// baseline (28730.023 us; speedup 1.0000x reference)
//
#include <hip/hip_runtime.h>

// Persistent 4-layer LSTM, fp32, layer-pipelined wavefront.
// HIDDEN=256, BATCH=32, SEQ=1024, LAYERS=4.
//
// Grid: 256 WGs x 256 threads. WG (l, part): part = jc*2 + bc,
//   jc in [0,32): owns hidden units [jc*8, jc*8+8) (all 4 gates = 32 gate rows)
//   bc in [0,2):  owns batches [bc*16, bc*16+16)
// Weights (W||R rows, K=512) cached in LDS once. c-state in registers
// (unique owner thread per (j,b) cell). Inter-layer h buffers = x_data slabs
// 1..3 (documented as inter-layer workspace); layer 3 writes d_out directly.
// Per-(layer,t) completion counters in d_ws; producer: __threadfence (agent
// fence -> L2 writeback, needed cross-XCD) + release atomicAdd; consumer:
// relaxed spin + fence (invalidates L1/L2 before reading fresh h/x).

#define HID   256
#define BAT   32
#define SEQL  1024
#define NLAY  4
#define NE    (HID*BAT)        // 8192
#define WGPL  64               // workgroups per layer
#define JCH   8                // hidden units per WG
#define BCH   16               // batches per WG
#define NROWS 32               // 4 gates * JCH
#define KTOT  (2*HID)          // W row (256) || R row (256)
#define WSTR  516              // padded LDS row stride (516 % 32 == 4, 16B-aligned)

__device__ __forceinline__ float sigm(float x)  { return 1.0f / (1.0f + __expf(-x)); }
__device__ __forceinline__ float tanhx(float x) { return 1.0f - 2.0f / (__expf(2.0f * x) + 1.0f); }

__global__ __launch_bounds__(256)
void lstm_persist(const float* __restrict__ h_data,
                  const float* __restrict__ c_data,
                  const float* __restrict__ W,
                  const float* __restrict__ R,
                  const float* __restrict__ bias,
                  float* xbuf,      // x_data base: slab 0 = input, slabs 1..3 = inter-layer h
                  float* out,       // d_out: layer-3 h for all t
                  int*   flags)     // [NLAY][SEQL] completion counters (pre-zeroed)
{
    __shared__ float lds_w[NROWS * WSTR];
    __shared__ float lds_g[4 * JCH * BCH];

    const int tid  = threadIdx.x;
    const int wg   = blockIdx.x;
    const int l    = wg >> 6;          // layer
    const int part = wg & 63;
    const int jc   = part >> 1;
    const int bc   = part & 1;
    const int jbase = jc * JCH;
    const int bbase = bc * BCH;

    // thread coords: 256 = 16 b  x 2 gate-pairs x 8 j
    const int j  = tid & 7;
    const int gp = (tid >> 3) & 1;
    const int b  = tid >> 4;
    const int bb = bbase + b;

    const int g0 = 2 * gp, g1 = 2 * gp + 1;
    const int r0 = g0 * JCH + j, r1 = g1 * JCH + j;       // local LDS rows
    const int grow0 = g0 * HID + jbase + j;               // global gate rows
    const int grow1 = g1 * HID + jbase + j;

    // ---- stage this WG's W||R rows into LDS (once) ----
    {
        const float* Wl = W + (size_t)l * 4 * HID * HID;
        const float* Rl = R + (size_t)l * 4 * HID * HID;
        for (int idx = tid * 4; idx < NROWS * KTOT; idx += 256 * 4) {
            int rl = idx >> 9;          // /512: local row (gate-major)
            int k  = idx & 511;
            int gr = (rl >> 3) * HID + jbase + (rl & 7);
            float4 v;
            if (k < HID) v = *(const float4*)(Wl + (size_t)gr * HID + k);
            else         v = *(const float4*)(Rl + (size_t)gr * HID + (k - HID));
            *(float4*)(&lds_w[rl * WSTR + k]) = v;
        }
    }

    const float bias0 = bias[l * 4 * HID + grow0];
    const float bias1 = bias[l * 4 * HID + grow1];

    // c-state: owner = gp==0 thread of each (j,b) cell
    float cst = 0.0f;
    if (gp == 0)
        cst = c_data[(size_t)l * (SEQL + 1) * NE + bb * HID + jbase + j];

    const float* h0  = h_data + (size_t)l * (SEQL + 1) * NE;   // [:,0] slice base
    const float* xin = xbuf + (size_t)l * SEQL * NE;
    float* hout = (l == NLAY - 1) ? out : (xbuf + (size_t)(l + 1) * SEQL * NE);

    __syncthreads();

    const float* w0p = &lds_w[r0 * WSTR];
    const float* w1p = &lds_w[r1 * WSTR];

    for (int t = 0; t < SEQL; ++t) {
        // ---- wait for dependencies ----
        if (tid == 0) {
            if (t > 0) {
                while (__hip_atomic_load(&flags[l * SEQL + t - 1],
                                         __ATOMIC_RELAXED, __HIP_MEMORY_SCOPE_AGENT) < WGPL)
                    __builtin_amdgcn_s_sleep(1);
            }
            if (l > 0) {
                while (__hip_atomic_load(&flags[(l - 1) * SEQL + t],
                                         __ATOMIC_RELAXED, __HIP_MEMORY_SCOPE_AGENT) < WGPL)
                    __builtin_amdgcn_s_sleep(1);
            }
        }
        __syncthreads();
        __threadfence();   // acquire side: invalidate L1/L2, see producers' stores

        const float* xrow = xin + (size_t)t * NE + bb * HID;
        const float* hrow = (t == 0) ? (h0 + bb * HID)
                                     : (hout + (size_t)(t - 1) * NE + bb * HID);

        // ---- gates = x @ W^T + h @ R^T + bias (2 rows per thread) ----
        float a0 = 0.f, a1 = 0.f, e0 = 0.f, e1 = 0.f;
        #pragma unroll 8
        for (int k = 0; k < HID; k += 4) {
            float4 xv = *(const float4*)(xrow + k);
            float4 w0 = *(const float4*)(w0p + k);
            float4 w1 = *(const float4*)(w1p + k);
            a0 = fmaf(w0.x, xv.x, a0); a0 = fmaf(w0.y, xv.y, a0);
            a0 = fmaf(w0.z, xv.z, a0); a0 = fmaf(w0.w, xv.w, a0);
            a1 = fmaf(w1.x, xv.x, a1); a1 = fmaf(w1.y, xv.y, a1);
            a1 = fmaf(w1.z, xv.z, a1); a1 = fmaf(w1.w, xv.w, a1);
        }
        #pragma unroll 8
        for (int k = 0; k < HID; k += 4) {
            float4 hv = *(const float4*)(hrow + k);
            float4 w0 = *(const float4*)(w0p + HID + k);
            float4 w1 = *(const float4*)(w1p + HID + k);
            e0 = fmaf(w0.x, hv.x, e0); e0 = fmaf(w0.y, hv.y, e0);
            e0 = fmaf(w0.z, hv.z, e0); e0 = fmaf(w0.w, hv.w, e0);
            e1 = fmaf(w1.x, hv.x, e1); e1 = fmaf(w1.y, hv.y, e1);
            e1 = fmaf(w1.z, hv.z, e1); e1 = fmaf(w1.w, hv.w, e1);
        }
        float acc0 = bias0 + a0 + e0;
        float acc1 = bias1 + a1 + e1;

        // ---- exchange gates via LDS, elementwise update by owner ----
        lds_g[(g0 * JCH + j) * BCH + b] = acc0;
        lds_g[(g1 * JCH + j) * BCH + b] = acc1;
        __syncthreads();
        if (gp == 0) {
            float iv = sigm (lds_g[(0 * JCH + j) * BCH + b]);
            float fv = sigm (lds_g[(1 * JCH + j) * BCH + b]);
            float gv = tanhx(lds_g[(2 * JCH + j) * BCH + b]);
            float ov = sigm (lds_g[(3 * JCH + j) * BCH + b]);
            cst = fv * cst + iv * gv;
            float hv = ov * tanhx(cst);
            hout[(size_t)t * NE + bb * HID + jbase + j] = hv;
        }
        __syncthreads();   // h stores drained (vmcnt(0) before barrier); protects lds_g WAR

        // ---- publish: L2 writeback then release-increment ----
        if (tid == 0) {
            __threadfence();
            __hip_atomic_fetch_add(&flags[l * SEQL + t], 1,
                                   __ATOMIC_RELEASE, __HIP_MEMORY_SCOPE_AGENT);
        }
    }
}

extern "C" void kernel_launch(void* const* d_in, const int* in_sizes, int n_in,
                              void* d_out, int out_size, void* d_ws, size_t ws_size,
                              hipStream_t stream) {
    const float* h_data = (const float*)d_in[0];
    float*       x_data = (float*)d_in[1];        // slabs 1..3 used as inter-layer ws
    const float* c_data = (const float*)d_in[2];
    const float* W      = (const float*)d_in[3];
    const float* R      = (const float*)d_in[4];
    const float* bias   = (const float*)d_in[5];
    float* out = (float*)d_out;

    const size_t flag_bytes = (size_t)NLAY * SEQL * sizeof(int);
    int* flags;
    if (ws_size >= flag_bytes) {
        flags = (int*)d_ws;
    } else {
        // fallback: tail slab 4 of x_data (SEQ*(LAYERS+1)*NE total, slab 4 unused)
        flags = (int*)(x_data + (size_t)4 * SEQL * NE);
    }
    hipMemsetAsync(flags, 0, flag_bytes, stream);

    lstm_persist<<<dim3(NLAY * WGPL), dim3(256), 0, stream>>>(
        h_data, c_data, W, R, bias, x_data, out, flags);
}

// Round 2
// 7202.996 us; speedup vs baseline: 3.9886x; 3.9886x over previous
//
#include <hip/hip_runtime.h>

// Persistent 4-layer LSTM, MFMA split-bf16, fence-free sc0sc1 coherence.
// H=256, B=32, SEQ=1024, L=4.
//
// Grid: 128 WGs x 256 thr. WG (l, w): layer l (bx>>5), owns units [w*8, w*8+8)
// x 4 gates = 32 gate-rows x all 32 batches. GEMM/step: D[m=32 batch][n=32 rows]
// = v[32][512] * Wcat^T, K = 512 (x(256) || h(256)).
// Wave q: mh=q&1 (batch half), nh=q>>1 (row half) -> one 16x16 C-tile.
// Weights resident in VGPRs as bf16 hi/lo (3-term split: hh + hl + lh).
// v comes from global packed-dword buffers ((hi<<16)|lo), loaded with sc0 sc1
// (coherence-point) asm loads -> no fences needed. Flags: relaxed agent atomics.
// hbuf[l][s] = h-state after s steps, stored in h_data slots s>=1 (unused by
// reference; harness restores inputs each launch). s=0 (h0) read as fp32.
// Layer-0 x pre-packed in place in x_data slab 0 by pack_x kernel.

#define HID  256
#define BAT  32
#define SEQL 1024
#define NLAY 4
#define NE   (HID*BAT)       // 8192
#define WGPL 32              // WGs per layer
#define GSTR 36              // lds gate-exchange row stride (floats)

typedef __attribute__((ext_vector_type(8))) short bf16x8;
typedef __attribute__((ext_vector_type(4))) float f32x4;

union U8 { bf16x8 v; unsigned short s[8]; unsigned u[4]; };

__device__ __forceinline__ unsigned short bf16_rne(float f) {
    unsigned u = __float_as_uint(f);
    u += 0x7FFFu + ((u >> 16) & 1u);
    return (unsigned short)(u >> 16);
}
__device__ __forceinline__ float bf16_to_f(unsigned short h) {
    return __uint_as_float(((unsigned)h) << 16);
}
__device__ __forceinline__ unsigned pack_hl(float f) {
    unsigned short hi = bf16_rne(f);
    unsigned short lo = bf16_rne(f - bf16_to_f(hi));
    return (((unsigned)hi) << 16) | lo;
}

__device__ __forceinline__ uint4 ld_cohx4(const unsigned* p) {
    uint4 r;
    asm volatile("global_load_dwordx4 %0, %1, off sc0 sc1" : "=v"(r) : "v"(p) : "memory");
    return r;
}
__device__ __forceinline__ void st_coh(unsigned* p, unsigned v) {
    asm volatile("global_store_dword %0, %1, off sc0 sc1" :: "v"(p), "v"(v) : "memory");
}
__device__ __forceinline__ void waitcnt0() {
    asm volatile("s_waitcnt vmcnt(0)" ::: "memory");
}

__device__ __forceinline__ float sigm(float x)  { return 1.0f / (1.0f + __expf(-x)); }
__device__ __forceinline__ float tanhx(float x) { return 1.0f - 2.0f / (__expf(2.0f * x) + 1.0f); }

// In-place pack of layer-0 input x: fp32 -> (bf16hi<<16)|bf16lo, elementwise.
__global__ __launch_bounds__(256) void pack_x(unsigned* xp) {
    int i = (blockIdx.x * 256 + threadIdx.x) * 4;   // SEQ*NE = 8192*1024 covered exactly
    float4 f = *(const float4*)((const float*)xp + i);
    uint4 u;
    u.x = pack_hl(f.x); u.y = pack_hl(f.y);
    u.z = pack_hl(f.z); u.w = pack_hl(f.w);
    *(uint4*)(xp + i) = u;
}

__global__ __launch_bounds__(256, 1)
void lstm_mfma(unsigned* __restrict__ hslab,       // h_data as dwords (slots s>=1 = hbuf)
               const float* __restrict__ c_data,
               const float* __restrict__ W,
               const float* __restrict__ R,
               const float* __restrict__ bias,
               const unsigned* __restrict__ xpack,  // x_data slab 0, packed
               float* __restrict__ out,
               int* __restrict__ flags)
{
    __shared__ float ldsg[32 * GSTR];

    const int tid  = threadIdx.x;
    const int bx   = blockIdx.x;
    const int l    = bx >> 5;
    const int w    = bx & 31;

    const int wv   = tid >> 6;
    const int lane = tid & 63;
    const int mh   = wv & 1;          // batch half
    const int nh   = wv >> 1;         // row half
    const int ln15 = lane & 15;
    const int kq   = lane >> 4;       // 0..3 k-block

    const int n_loc = nh * 16 + ln15;             // local gate-row 0..31
    const int gate  = n_loc >> 3;
    const int uu    = n_loc & 7;
    const int grow  = gate * HID + w * 8 + uu;    // global gate-row in [0,1024)
    const int bg    = mh * 16 + ln15;             // batch for A-frags

    // ---- resident weight fragments: Bhi/Blo[s], s=0..15 (K=512) ----
    bf16x8 Bhi[16], Blo[16];
    {
        const float* Wl = W + (size_t)l * 4 * HID * HID;
        const float* Rl = R + (size_t)l * 4 * HID * HID;
        #pragma unroll
        for (int s = 0; s < 16; ++s) {
            int k0 = s * 32 + kq * 8;
            const float* src = (k0 < HID) ? (Wl + (size_t)grow * HID + k0)
                                          : (Rl + (size_t)grow * HID + (k0 - HID));
            float4 f0 = *(const float4*)src;
            float4 f1 = *(const float4*)(src + 4);
            float ff[8] = {f0.x, f0.y, f0.z, f0.w, f1.x, f1.y, f1.z, f1.w};
            U8 hi, lo;
            #pragma unroll
            for (int j = 0; j < 8; ++j) {
                hi.s[j] = bf16_rne(ff[j]);
                lo.s[j] = bf16_rne(ff[j] - bf16_to_f(hi.s[j]));
            }
            Bhi[s] = hi.v; Blo[s] = lo.v;
        }
    }

    const float bias_n = bias[l * 4 * HID + grow];

    // c-state owner: thread (uu2, b2)
    const int uu2 = tid >> 5;
    const int b2  = tid & 31;
    float cst = c_data[(size_t)l * (SEQL + 1) * NE + b2 * HID + w * 8 + uu2];

    unsigned* hbuf = hslab;  // slot (l,s) at ((l*(SEQL+1))+s)*NE
    const float* h0f = (const float*)hslab + (size_t)l * (SEQL + 1) * NE;

    for (int t = 0; t < SEQL; ++t) {
        // ---- dependency wait (no fences; data goes through coherence point) ----
        if (tid == 0) {
            if (t > 0)
                while (__hip_atomic_load(&flags[l * SEQL + t - 1],
                       __ATOMIC_RELAXED, __HIP_MEMORY_SCOPE_AGENT) < WGPL)
                    __builtin_amdgcn_s_sleep(1);
            if (l > 0)
                while (__hip_atomic_load(&flags[(l - 1) * SEQL + t],
                       __ATOMIC_RELAXED, __HIP_MEMORY_SCOPE_AGENT) < WGPL)
                    __builtin_amdgcn_s_sleep(1);
        }
        __syncthreads();

        const unsigned* xsrc = (l == 0)
            ? (xpack + (size_t)t * NE)
            : (hbuf + ((size_t)(l - 1) * (SEQL + 1) + (t + 1)) * NE);

        // ---- issue A-fragment loads (x-part s<8, h-part s>=8) ----
        uint4 araw[32];
        if (t > 0) {
            const unsigned* hsrc = hbuf + ((size_t)l * (SEQL + 1) + t) * NE;
            #pragma unroll
            for (int s = 0; s < 16; ++s) {
                const unsigned* p = (s < 8)
                    ? (xsrc + bg * HID + s * 32 + kq * 8)
                    : (hsrc + bg * HID + (s - 8) * 32 + kq * 8);
                araw[2 * s]     = ld_cohx4(p);
                araw[2 * s + 1] = ld_cohx4(p + 4);
            }
            asm volatile("s_waitcnt vmcnt(16)" ::: "memory");  // x-part ready
        } else {
            #pragma unroll
            for (int s = 0; s < 8; ++s) {
                const unsigned* p = xsrc + bg * HID + s * 32 + kq * 8;
                araw[2 * s]     = ld_cohx4(p);
                araw[2 * s + 1] = ld_cohx4(p + 4);
            }
            #pragma unroll
            for (int s = 8; s < 16; ++s) {   // h0 is fp32 in h_data slot 0
                const float* hp = h0f + bg * HID + (s - 8) * 32 + kq * 8;
                float4 f0 = *(const float4*)hp;
                float4 f1 = *(const float4*)(hp + 4);
                uint4 a0, a1;
                a0.x = pack_hl(f0.x); a0.y = pack_hl(f0.y);
                a0.z = pack_hl(f0.z); a0.w = pack_hl(f0.w);
                a1.x = pack_hl(f1.x); a1.y = pack_hl(f1.y);
                a1.z = pack_hl(f1.z); a1.w = pack_hl(f1.w);
                araw[2 * s] = a0; araw[2 * s + 1] = a1;
            }
            waitcnt0();
        }

        // ---- MFMA K-loop: 3-term split-bf16, 3 independent acc chains ----
        f32x4 acc0 = {bias_n, bias_n, bias_n, bias_n};
        f32x4 acc1 = {0.f, 0.f, 0.f, 0.f};
        f32x4 acc2 = {0.f, 0.f, 0.f, 0.f};
        #pragma unroll
        for (int s = 0; s < 16; ++s) {
            if (s == 8 && t > 0) waitcnt0();   // h-part ready
            uint4 d0 = araw[2 * s], d1 = araw[2 * s + 1];
            U8 ahi, alo;
            ahi.u[0] = __builtin_amdgcn_perm(d0.y, d0.x, 0x07060302u);
            ahi.u[1] = __builtin_amdgcn_perm(d0.w, d0.z, 0x07060302u);
            ahi.u[2] = __builtin_amdgcn_perm(d1.y, d1.x, 0x07060302u);
            ahi.u[3] = __builtin_amdgcn_perm(d1.w, d1.z, 0x07060302u);
            alo.u[0] = __builtin_amdgcn_perm(d0.y, d0.x, 0x05040100u);
            alo.u[1] = __builtin_amdgcn_perm(d0.w, d0.z, 0x05040100u);
            alo.u[2] = __builtin_amdgcn_perm(d1.y, d1.x, 0x05040100u);
            alo.u[3] = __builtin_amdgcn_perm(d1.w, d1.z, 0x05040100u);
            acc0 = __builtin_amdgcn_mfma_f32_16x16x32_bf16(ahi.v, Bhi[s], acc0, 0, 0, 0);
            acc1 = __builtin_amdgcn_mfma_f32_16x16x32_bf16(ahi.v, Blo[s], acc1, 0, 0, 0);
            acc2 = __builtin_amdgcn_mfma_f32_16x16x32_bf16(alo.v, Bhi[s], acc2, 0, 0, 0);
        }
        f32x4 cc = acc0 + acc1;
        cc = cc + acc2;

        // ---- exchange gates via LDS: ldsg[n][m], D: m=(lane>>4)*4+r, n=lane&15 ----
        *(f32x4*)&ldsg[n_loc * GSTR + mh * 16 + kq * 4] = cc;
        __syncthreads();

        // ---- elementwise update by cell owner (uu2, b2) ----
        {
            float gi = ldsg[(0 * 8 + uu2) * GSTR + b2];
            float gf = ldsg[(1 * 8 + uu2) * GSTR + b2];
            float gg = ldsg[(2 * 8 + uu2) * GSTR + b2];
            float go = ldsg[(3 * 8 + uu2) * GSTR + b2];
            float iv = sigm(gi), fv = sigm(gf), gv = tanhx(gg), ov = sigm(go);
            cst = fv * cst + iv * gv;
            float hv = ov * tanhx(cst);
            unsigned dw = pack_hl(hv);
            unsigned* dst = hbuf + ((size_t)l * (SEQL + 1) + (t + 1)) * NE
                          + b2 * HID + w * 8 + uu2;
            st_coh(dst, dw);
            if (l == NLAY - 1)
                out[(size_t)t * NE + b2 * HID + w * 8 + uu2] = hv;
        }
        waitcnt0();          // every wave drains its own h stores
        __syncthreads();

        if (tid == 0)
            __hip_atomic_fetch_add(&flags[l * SEQL + t], 1,
                                   __ATOMIC_RELAXED, __HIP_MEMORY_SCOPE_AGENT);
    }
}

extern "C" void kernel_launch(void* const* d_in, const int* in_sizes, int n_in,
                              void* d_out, int out_size, void* d_ws, size_t ws_size,
                              hipStream_t stream) {
    unsigned*    h_data = (unsigned*)d_in[0];
    unsigned*    x_data = (unsigned*)d_in[1];
    float*       c_data = (float*)d_in[2];
    const float* W      = (const float*)d_in[3];
    const float* R      = (const float*)d_in[4];
    const float* bias   = (const float*)d_in[5];
    float* out = (float*)d_out;

    const size_t flag_bytes = (size_t)NLAY * SEQL * sizeof(int);
    int* flags;
    if (ws_size >= flag_bytes) flags = (int*)d_ws;
    else                       flags = (int*)(c_data + NE);  // c_data slot [0][1]: unused
    hipMemsetAsync(flags, 0, flag_bytes, stream);

    // pack layer-0 x in place (SEQ*NE elements = 8192 blocks * 256 thr * 4)
    pack_x<<<dim3(8192), dim3(256), 0, stream>>>(x_data);

    lstm_mfma<<<dim3(NLAY * WGPL), dim3(256), 0, stream>>>(
        h_data, c_data, W, R, bias, x_data, out, flags);
}